// Round 20
// baseline (107.407 us; speedup 1.0000x reference)
//
#include <hip/hip_runtime.h>

// ---------------------------------------------------------------------------
// attention_76089640615954 on MI355X (gfx950)
// x:[1,256,64,64] -> 1x1 conv (3C) -> 11x11 depthwise -> 8-head attn (N=4096,
// d=32, temp=5) -> 1x1 conv + bias -> relu + residual.
// fp16 MFMA (16x16x32), fp32 accumulate, fixed-shift softmax (per-coordinate
// bound C = sum_d |q_d|*kmaxd[h][d], kmaxd from dwconv; shift in MFMA C-op).
// R20: clean barrier-density test in attn -- 2 chunks per sync point, all
// else bit-identical to the R14-verified structure (64-key chunks, 4x4KB
// buffers, same staging addresses/swizzles). Barriers 16 -> 8 per block.
// R15's version of this spilled because it also widened staging; this one
// adds zero per-wave state. Tripwire: attn WRITE_SIZE must stay ~2MB.
// ---------------------------------------------------------------------------

typedef _Float16 f16;
typedef __fp16 hf16x2 __attribute__((ext_vector_type(2)));
typedef _Float16 f16x4 __attribute__((ext_vector_type(4)));
typedef _Float16 f16x8 __attribute__((ext_vector_type(8)));
typedef float f32x4 __attribute__((ext_vector_type(4)));

#define HW 4096      // 64*64 pixels
#define NC 256       // channels

#if __has_builtin(__builtin_amdgcn_exp2f)
#define EXP2(x) __builtin_amdgcn_exp2f(x)
#else
#define EXP2(x) exp2f(x)
#endif

static __device__ __forceinline__ f32x4 mfma16(f16x8 a, f16x8 b, f32x4 c) {
  return __builtin_amdgcn_mfma_f32_16x16x32_f16(a, b, c, 0, 0, 0);
}

static __device__ __forceinline__ void gload16(const void* g, void* l) {
  __builtin_amdgcn_global_load_lds(
      (const __attribute__((address_space(1))) unsigned int*)g,
      (__attribute__((address_space(3))) unsigned int*)l, 16, 0, 0);
}

static __device__ __forceinline__ f16x8 load_a_f32(const float* p) {
  f32x4 lo = *(const f32x4*)p, hi = *(const f32x4*)(p + 4);
  f16x8 a;
#pragma unroll
  for (int j = 0; j < 4; j++) {
    a[j] = (f16)lo[j];
    a[4 + j] = (f16)hi[j];
  }
  return a;
}

// ------------- GEMM1: qkv = Wpw[768,256] * x (+bias) -> f16 ----------------
// B tile staged straight from f32 x (in-block transpose, RTN casts) into the
// swizzled layout; A rows read f32-direct. Zero-inits kmaxd. (R19-verified)
__global__ __launch_bounds__(256) void k_gemm_qkv(
    const float* __restrict__ w, const float* __restrict__ x,
    const float* __restrict__ bias, f16* __restrict__ out,
    int* __restrict__ kmaxd_bits) {
  __shared__ f16 lds_b[64 * 256];  // 32KB [pix][ch-slot], swizzled
  int bm = blockIdx.x >> 6;   // 6
  int bn = blockIdx.x & 63;   // 64
  int tid = threadIdx.x;
  int wave = tid >> 6, lane = tid & 63;
  int r = lane & 15, g = lane >> 4;
  int m0 = bm * 128 + wave * 32;
  int n0 = bn * 64;
  kmaxd_bits[tid] = 0;  // all blocks store 0: benign, ready before dwconv
#pragma unroll
  for (int round = 0; round < 4; ++round) {
    int task = round * 256 + tid;
    int pg = task & 15, cg = task >> 4;  // pg: consecutive lanes -> coalesced
    int p0 = pg * 4, c0 = cg * 4;
    f32x4 v[4];
#pragma unroll
    for (int cc = 0; cc < 4; cc++)
      v[cc] = *(const f32x4*)&x[(c0 + cc) * HW + n0 + p0];
#pragma unroll
    for (int pp = 0; pp < 4; pp++) {
      int row = p0 + pp;
      f16x4 o;
#pragma unroll
      for (int cc = 0; cc < 4; cc++) o[cc] = (f16)v[cc][pp];  // RTN
      int byteoff =
          row * 512 + (((c0 >> 3) ^ (row & 7)) << 4) + (c0 & 4) * 2;
      *(f16x4*)((char*)lds_b + byteoff) = o;
    }
  }
  __syncthreads();
  f32x4 acc[2][4] = {};
  for (int kk = 0; kk < NC; kk += 32) {
    f16x8 a0 = load_a_f32(&w[(m0 + r) * NC + kk + g * 8]);
    f16x8 a1 = load_a_f32(&w[(m0 + 16 + r) * NC + kk + g * 8]);
    int sb = (kk >> 3) + g;  // data slot
#pragma unroll
    for (int nt = 0; nt < 4; nt++) {
      int row = nt * 16 + r;
      f16x8 bfr = *(const f16x8*)((char*)lds_b + row * 512 +
                                  ((sb ^ (row & 7)) * 16));
      acc[0][nt] = mfma16(a0, bfr, acc[0][nt]);
      acc[1][nt] = mfma16(a1, bfr, acc[1][nt]);
    }
  }
#pragma unroll
  for (int mg = 0; mg < 2; mg++) {
    int mbase = m0 + mg * 16 + g * 4;
    float bj[4];
#pragma unroll
    for (int j = 0; j < 4; j++) bj[j] = bias[mbase + j];
#pragma unroll
    for (int nt = 0; nt < 4; nt++)
#pragma unroll
      for (int j = 0; j < 4; j++)
        out[(mbase + j) * HW + n0 + nt * 16 + r] =
            (f16)(acc[mg][nt][j] + bj[j]);
  }
}

// ------------------- depthwise 11x11, pad 5, groups=768 --------------------
// 2 half-image blocks per channel; vectorized f16x8 image loads (R14).
// K-channel blocks compute per-(h,d) max|k| -> atomicMax (uniform branch).
__global__ __launch_bounds__(256) void k_dwconv(
    const f16* __restrict__ qkv, const float* __restrict__ wdw,
    const float* __restrict__ bdw, f16* __restrict__ q_nm,
    f16* __restrict__ k_nm, f16* __restrict__ v_cm,
    int* __restrict__ kmaxd_bits) {
  __shared__ float img[42 * 74];
  __shared__ float wgt[121];
  int b = blockIdx.x;
  int c = b >> 1, half = b & 1;
  int y0 = half * 32;
  int tid = threadIdx.x;
  for (int i = tid; i < 420; i += 256) {
    int row = i / 10, cc = i - row * 10;
    img[row * 74 + (cc < 5 ? cc : 64 + cc)] = 0.f;
  }
  const f16x8 zv = {};
  for (int task = tid; task < 336; task += 256) {
    int row = task >> 3, ch = task & 7;
    int y = y0 + row - 5;
    f16x8 v = ((unsigned)y < 64u)
                  ? *(const f16x8*)&qkv[c * HW + y * 64 + ch * 8]
                  : zv;
    float* dst = &img[row * 74 + 5 + ch * 8];
#pragma unroll
    for (int j = 0; j < 8; j++) dst[j] = (float)v[j];
  }
  for (int i = tid; i < 121; i += 256) wgt[i] = wdw[c * 121 + i];
  __syncthreads();
  float bias = bdw[c];
  int px0 = half * 2048 + tid * 8;
  int yl = tid >> 3;         // local row 0..31
  int x0 = (tid & 7) * 8;
  float acc[8] = {};
#pragma unroll
  for (int ky = 0; ky < 11; ky++) {
    const float* rp = &img[(yl + ky) * 74 + x0];
    float rv[18];
#pragma unroll
    for (int t = 0; t < 18; t++) rv[t] = rp[t];
#pragma unroll
    for (int kx = 0; kx < 11; kx++) {
      float wv = wgt[ky * 11 + kx];
#pragma unroll
      for (int p = 0; p < 8; p++) acc[p] = fmaf(rv[kx + p], wv, acc[p]);
    }
  }
  if (c < 256) {
    int h = c >> 5, d = c & 31;
#pragma unroll
    for (int p = 0; p < 8; p++)
      q_nm[(h * HW + px0 + p) * 32 + d] =
          (f16)((acc[p] + bias) * 0.28853900817779268f);  // 0.2*log2(e)
  } else if (c < 512) {
    int cc = c - 256;
    int h = cc >> 5, d = cc & 31;
    float m = 0.f;
#pragma unroll
    for (int p = 0; p < 8; p++) {
      float kv = acc[p] + bias;
      k_nm[(h * HW + px0 + p) * 32 + d] = (f16)kv;
      m = fmaxf(m, fabsf(kv));
    }
    __syncthreads();
    img[tid] = m;
    __syncthreads();
    for (int off = 128; off > 0; off >>= 1) {
      if (tid < off) img[tid] = fmaxf(img[tid], img[tid + off]);
      __syncthreads();
    }
    if (tid == 0) atomicMax(&kmaxd_bits[cc], __float_as_int(img[0]));
  } else {
    int cc = c - 512;
#pragma unroll
    for (int p = 0; p < 8; p++)
      v_cm[cc * HW + px0 + p] = (f16)(acc[p] + bias);
  }
}

// ----------------------------- flash attention -----------------------------
// R14 structure; R20: 2 chunks per sync point. Block = 512 threads = 8 waves
// x 32 q-rows (256-row q-tile); key-quarter per block; 16 LDS-staged 64-key
// chunks, 4-deep. Loop steps t+=2: issue gloads for chunks t+2,t+3 ->
// s_waitcnt vmcnt(2) (own t,t+1 landed) -> raw s_barrier -> compute chunk t
// then t+1. Barriers/block 16 -> 8; staging addresses and per-wave register
// state identical to R14. Waves 0-3 stage K, 4-7 stage V; K LDS [key][d]
// slot^=(key>>3)&3 both-sides; V LDS [d][key] slot^=(d&7). Fixed-shift
// softmax; setprio around MFMA clusters; pre-normalized f16 partials + f32 L.
__global__ __launch_bounds__(512, 4) void k_attn(
    const f16* __restrict__ q_nm, const f16* __restrict__ k_nm,
    const f16* __restrict__ v_cm, const int* __restrict__ kmaxd_bits,
    f16* __restrict__ o_part, float* __restrict__ l_part) {
  __shared__ f16 lds_k[4][2048];  // 4 x 4KB: [key 0..63][d-slot], swizzled
  __shared__ f16 lds_v[4][2048];  // 4 x 4KB: [d 0..31][key-slot], swizzled
  int bid = blockIdx.x;
  int h = bid & 7, kq = (bid >> 3) & 3, qt = bid >> 5;  // qt 0..15
  int tid = threadIdx.x;
  int wv = tid >> 6, lane = tid & 63;
  int r = lane & 15, g = lane >> 4;
  int n_base = qt * 256 + wv * 32;
  int m_lo = kq << 10;  // 1024 keys per block
  const f16* qh = q_nm + h * (HW * 32);
  const f16* kh = k_nm + h * (HW * 32) + m_lo * 32;
  const f16* vh = v_cm + h * (32 * HW) + m_lo;

  f16x8 bq0 = *(const f16x8*)&qh[(n_base + r) * 32 + g * 8];
  f16x8 bq1 = *(const f16x8*)&qh[(n_base + 16 + r) * 32 + g * 8];
  // ---- per-coordinate bound: C = sum_d |q_d| * kmaxd[h][d] ----
  const float* kmd = (const float*)kmaxd_bits + h * 32 + g * 8;
  f32x4 kd0 = *(const f32x4*)kmd;
  f32x4 kd1 = *(const f32x4*)(kmd + 4);
  float ba = 0.f, bb = 0.f;
#pragma unroll
  for (int j = 0; j < 4; j++) {
    ba = fmaf(fabsf((float)bq0[j]), kd0[j], ba);
    ba = fmaf(fabsf((float)bq0[4 + j]), kd1[j], ba);
    bb = fmaf(fabsf((float)bq1[j]), kd0[j], bb);
    bb = fmaf(fabsf((float)bq1[4 + j]), kd1[j], bb);
  }
  ba += __shfl_xor(ba, 16);
  ba += __shfl_xor(ba, 32);
  bb += __shfl_xor(bb, 16);
  bb += __shfl_xor(bb, 32);
  float mCa = 13.9f - ba;
  float mCb = 13.9f - bb;
  f32x4 cinitA = {mCa, mCa, mCa, mCa};
  f32x4 cinitB = {mCb, mCb, mCb, mCb};
  int pr = ((r & 12) << 1) | (r & 3);  // 8*(r>>2)+(r&3)
  f32x4 accA0 = {0.f, 0.f, 0.f, 0.f}, accA1 = {0.f, 0.f, 0.f, 0.f};
  f32x4 accB0 = {0.f, 0.f, 0.f, 0.f}, accB1 = {0.f, 0.f, 0.f, 0.f};
  float La = 0.f, Lb = 0.f;

  // ---- staging addresses (chunk 0); 16B per lane per chunk ----
  int l4 = lane >> 2, l3 = lane & 3;
  int kc = (wv & 3) * 16 + l4;
  int ku = (kc >> 3) & 3;
  const f16* kg_base = kh + kc * 32 + (l3 ^ ku) * 8;
  int t2v = (tid >= 256) ? tid - 256 : 0;
  int vd = t2v >> 3;
  int vkk = ((t2v & 7) ^ (vd & 7)) * 8;
  const f16* vg_base = vh + vd * HW + vkk;
  f16* kdst = &lds_k[0][0] + (wv & 3) * 512;   // + buf*2048
  f16* vdst = &lds_v[0][0] + (t2v >> 6) * 512; // wv-4

  // ---- consumer LDS byte offsets (loop-invariant) ----
  int u = r >> 2;
  int kslot = ((g ^ u) & 3) * 16;
  int ak0_off = pr * 64 + kslot;          // ks=0; ks=1: +2048
  int ak1_off = (pr + 4) * 64 + kslot;
  int vb_off0 = (r * 128 + g * 16) ^ ((r & 7) << 4);       // ks=0
  int vb_off1 = (r * 128 + 64 + g * 16) ^ ((r & 7) << 4);  // ks=1

  // ---- prologue: drain q/kmaxd loads, prefetch chunks 0,1 ----
  __builtin_amdgcn_s_waitcnt(0);
  if (wv < 4) {
    gload16(kg_base, kdst);
    gload16(kg_base + 2048, kdst + 2048);
  } else {
    gload16(vg_base, vdst);
    gload16(vg_base + 64, vdst + 2048);
  }

  for (int t = 0; t < 16; t += 2) {
    int c2 = (t + 2 <= 15) ? t + 2 : 15;  // clamp: redundant restage, unread
    int c3 = (t + 3 <= 15) ? t + 3 : 15;
    int b2 = (t + 2) & 3, b3 = (t + 3) & 3;
    if (wv < 4) {
      gload16(kg_base + c2 * 2048, kdst + b2 * 2048);
      gload16(kg_base + c3 * 2048, kdst + b3 * 2048);
    } else {
      gload16(vg_base + c2 * 64, vdst + b2 * 2048);
      gload16(vg_base + c3 * 64, vdst + b3 * 2048);
    }
    asm volatile("s_waitcnt vmcnt(2)" ::: "memory");
    __builtin_amdgcn_sched_barrier(0);
    __builtin_amdgcn_s_barrier();
    __builtin_amdgcn_sched_barrier(0);
#pragma unroll
    for (int half = 0; half < 2; ++half) {
      int tc = t + half;
      const char* kb = (const char*)&lds_k[tc & 3][0];
      const char* vb = (const char*)&lds_v[tc & 3][0];
#pragma unroll
      for (int ks = 0; ks < 2; ++ks) {
        f16x8 ak0 = *(const f16x8*)(kb + ks * 2048 + ak0_off);
        f16x8 ak1 = *(const f16x8*)(kb + ks * 2048 + ak1_off);
        int vo = ks ? vb_off1 : vb_off0;
        f16x8 bv0 = *(const f16x8*)(vb + vo);          // V[d=r][...]
        f16x8 bv1 = *(const f16x8*)(vb + vo + 2048);   // V[d=16+r][...]
        __builtin_amdgcn_s_setprio(1);
        f32x4 sA0 = mfma16(ak0, bq0, cinitA);
        f32x4 sA1 = mfma16(ak1, bq0, cinitA);
        f32x4 sB0 = mfma16(ak0, bq1, cinitB);
        f32x4 sB1 = mfma16(ak1, bq1, cinitB);
        __builtin_amdgcn_s_setprio(0);
        float pA[8], pB[8];
#pragma unroll
        for (int j = 0; j < 4; j++) {
          pA[j] = EXP2(sA0[j]);
          pA[4 + j] = EXP2(sA1[j]);
          pB[j] = EXP2(sB0[j]);
          pB[4 + j] = EXP2(sB1[j]);
        }
        La += ((pA[0] + pA[1]) + (pA[2] + pA[3])) +
              ((pA[4] + pA[5]) + (pA[6] + pA[7]));
        Lb += ((pB[0] + pB[1]) + (pB[2] + pB[3])) +
              ((pB[4] + pB[5]) + (pB[6] + pB[7]));
        union { hf16x2 h2[4]; f16x8 v; } uA, uB;
#pragma unroll
        for (int j = 0; j < 4; j++) {
          uA.h2[j] = __builtin_amdgcn_cvt_pkrtz(pA[2 * j], pA[2 * j + 1]);
          uB.h2[j] = __builtin_amdgcn_cvt_pkrtz(pB[2 * j], pB[2 * j + 1]);
        }
        __builtin_amdgcn_s_setprio(1);
        accA0 = mfma16(uA.v, bv0, accA0);
        accA1 = mfma16(uA.v, bv1, accA1);
        accB0 = mfma16(uB.v, bv0, accB0);
        accB1 = mfma16(uB.v, bv1, accB1);
        __builtin_amdgcn_s_setprio(0);
      }
    }
  }
  // ---- pre-normalized partials -> workspace (f16 O/L, f32 L) ----
  La += __shfl_xor(La, 16);
  La += __shfl_xor(La, 32);
  Lb += __shfl_xor(Lb, 16);
  Lb += __shfl_xor(Lb, 32);
  float ilA = 1.f / La, ilB = 1.f / Lb;
  f16* op = o_part + ((((size_t)kq * 8 + h) * HW) + n_base) * 32;
#pragma unroll
  for (int j = 0; j < 4; j++) {
    float ija = __shfl(ilA, 4 * g + j);  // 1/L for row n_base+4g+j
    float ijb = __shfl(ilB, 4 * g + j);  // 1/L for row n_base+16+4g+j
    op[(4 * g + j) * 32 + r] = (f16)(accA0[j] * ija);
    op[(4 * g + j) * 32 + 16 + r] = (f16)(accA1[j] * ija);
    op[(16 + 4 * g + j) * 32 + r] = (f16)(accB0[j] * ijb);
    op[(16 + 4 * g + j) * 32 + 16 + r] = (f16)(accB1[j] * ijb);
  }
  if (lane < 16) {
    l_part[(((size_t)kq * 8 + h) * HW) + n_base + r] = La;
    l_part[(((size_t)kq * 8 + h) * HW) + n_base + 16 + r] = Lb;
  }
}

// ---- GEMM2 (fused norm_o): out = relu(Wlin * combine(o_part) + b) + x -----
__global__ __launch_bounds__(256) void k_gemm_proj(
    const float* __restrict__ w, const f16* __restrict__ o_part,
    const float* __restrict__ l_part, const float* __restrict__ bias,
    const float* __restrict__ x, float* __restrict__ out) {
  __shared__ f16 lds_b[32 * 256];  // 16KB
  int bm = blockIdx.x >> 7;   // 4
  int bn = blockIdx.x & 127;  // 128 n-tiles of 32
  int tid = threadIdx.x;
  int wave = tid >> 6, lane = tid & 63;
  int r = lane & 15, g = lane >> 4;
  int m_row = bm * 64 + wave * 16 + r;
  int n0 = bn * 32;
#pragma unroll
  for (int round = 0; round < 4; ++round) {
    int task = round * 256 + tid;
    int row = task >> 5, grp = task & 31;      // grp = 8-ch group
    int h = grp >> 2, d0 = (grp & 3) * 8;
    size_t rbase = ((size_t)h * HW) + n0 + row;
    float Lq[4];
    f16x8 oq[4];
#pragma unroll
    for (int q = 0; q < 4; q++) {
      Lq[q] = l_part[(size_t)q * 8 * HW + rbase];
      oq[q] = *(const f16x8*)&o_part[((size_t)q * 8 * HW + rbase) * 32 + d0];
    }
    float inv = 1.f / ((Lq[0] + Lq[1]) + (Lq[2] + Lq[3]));
    f16x8 outv;
#pragma unroll
    for (int j = 0; j < 8; j++) {
      float o = 0.f;
#pragma unroll
      for (int q = 0; q < 4; q++) o = fmaf((float)oq[q][j], Lq[q], o);
      outv[j] = (f16)(o * inv);
    }
    *(f16x8*)((char*)lds_b + row * 512 + ((grp ^ (row & 7)) * 16)) = outv;
  }
  __syncthreads();
  f32x4 acc[2] = {};
  for (int kk = 0; kk < NC; kk += 32) {
    f16x8 a = load_a_f32(&w[m_row * NC + kk + g * 8]);
    int sb = (kk >> 3) + g;  // data slot
#pragma unroll
    for (int nt = 0; nt < 2; nt++) {
      int row = nt * 16 + r;
      f16x8 bfr = *(const f16x8*)((char*)lds_b + row * 512 +
                                  ((sb ^ (row & 7)) * 16));
      acc[nt] = mfma16(a, bfr, acc[nt]);
    }
  }
  int mbase = bm * 64 + wave * 16 + g * 4;
  float bj[4];
#pragma unroll
  for (int j = 0; j < 4; j++) bj[j] = bias[mbase + j];
#pragma unroll
  for (int nt = 0; nt < 2; nt++)
#pragma unroll
    for (int j = 0; j < 4; j++) {
      int m = mbase + j, n = n0 + nt * 16 + r;
      float v = fmaxf(acc[nt][j] + bj[j], 0.f) + x[m * HW + n];
      out[m * HW + n] = v;
    }
}

// ---------------------------------------------------------------------------
extern "C" void kernel_launch(void* const* d_in, const int* in_sizes, int n_in,
                              void* d_out, int out_size, void* d_ws,
                              size_t ws_size, hipStream_t stream) {
  const float* x = (const float*)d_in[0];
  const float* w_pw = (const float*)d_in[1];
  const float* b_pw = (const float*)d_in[2];
  const float* w_dw = (const float*)d_in[3];
  const float* b_dw = (const float*)d_in[4];
  const float* w_lin = (const float*)d_in[5];
  const float* b_lin = (const float*)d_in[6];
  float* out = (float*)d_out;

  char* ws = (char*)d_ws;
  f16* qkv = (f16*)(ws + 2621440);        // 768*4096*2     = 6291456
  f16* q_nm = (f16*)(ws + 15204352);      // 8*4096*32*2    = 2097152
  f16* k_nm = (f16*)(ws + 17301504);      // 2097152
  f16* v_cm = (f16*)(ws + 19398656);      // 2097152
  int* kmaxd_bits = (int*)(ws + 23724032);  // 256*4 = 1024 bytes
  // partials alias qkv region (qkv dead after k_dwconv):
  // o_part f16 4*8*4096*32*2 = 8388608; l_part f32 4*8*4096*4 = 524288
  f16* o_part = (f16*)(ws + 2621440);
  float* l_part = (float*)(ws + 2621440 + 8388608);  // ends 11534336 < 15204352

  k_gemm_qkv<<<384, 256, 0, stream>>>(w_pw, x, b_pw, qkv, kmaxd_bits);
  k_dwconv<<<1536, 256, 0, stream>>>(qkv, w_dw, b_dw, q_nm, k_nm, v_cm,
                                     kmaxd_bits);
  k_attn<<<512, 512, 0, stream>>>(q_nm, k_nm, v_cm, kmaxd_bits, o_part,
                                  l_part);
  k_gemm_proj<<<512, 256, 0, stream>>>(w_lin, o_part, l_part, b_lin, x, out);
}

// Round 21
// 72.534 us; speedup vs baseline: 1.4808x; 1.4808x over previous
//
#include <hip/hip_runtime.h>

// ---------------------------------------------------------------------------
// attention_76089640615954 on MI355X (gfx950)
// x:[1,256,64,64] -> 1x1 conv (3C) -> 11x11 depthwise -> 8-head attn (N=4096,
// d=32, temp=5) -> 1x1 conv + bias -> relu + residual.
// fp16 MFMA (16x16x32), fp32 accumulate, fixed-shift softmax (per-coordinate
// bound C = sum_d |q_d|*kmaxd[h][d], kmaxd from dwconv; shift in MFMA C-op).
// R20 post-mortem: 2-chunks-per-barrier spilled AGAIN (WRITE 2MB->186MB) --
// the attn loop sits exactly on the regalloc cliff; any widening of the
// per-barrier compute body spills (3rd strike: R5, R15, R20). REVERT to the
// R19-verified 73.0us configuration; attn ~32us is this structure's floor.
// ---------------------------------------------------------------------------

typedef _Float16 f16;
typedef __fp16 hf16x2 __attribute__((ext_vector_type(2)));
typedef _Float16 f16x4 __attribute__((ext_vector_type(4)));
typedef _Float16 f16x8 __attribute__((ext_vector_type(8)));
typedef float f32x4 __attribute__((ext_vector_type(4)));

#define HW 4096      // 64*64 pixels
#define NC 256       // channels

#if __has_builtin(__builtin_amdgcn_exp2f)
#define EXP2(x) __builtin_amdgcn_exp2f(x)
#else
#define EXP2(x) exp2f(x)
#endif

static __device__ __forceinline__ f32x4 mfma16(f16x8 a, f16x8 b, f32x4 c) {
  return __builtin_amdgcn_mfma_f32_16x16x32_f16(a, b, c, 0, 0, 0);
}

static __device__ __forceinline__ void gload16(const void* g, void* l) {
  __builtin_amdgcn_global_load_lds(
      (const __attribute__((address_space(1))) unsigned int*)g,
      (__attribute__((address_space(3))) unsigned int*)l, 16, 0, 0);
}

static __device__ __forceinline__ f16x8 load_a_f32(const float* p) {
  f32x4 lo = *(const f32x4*)p, hi = *(const f32x4*)(p + 4);
  f16x8 a;
#pragma unroll
  for (int j = 0; j < 4; j++) {
    a[j] = (f16)lo[j];
    a[4 + j] = (f16)hi[j];
  }
  return a;
}

// ------------- GEMM1: qkv = Wpw[768,256] * x (+bias) -> f16 ----------------
// B tile (64 px x 256 ch) staged straight from f32 x with an in-block
// transpose (4px x 4ch micro-tiles, RTN casts, ds_write_b64) into the same
// swizzled layout the R14-verified read path expects. A rows read f32-direct.
// Also zero-inits kmaxd_bits (dwconv atomicMax runs strictly after).
__global__ __launch_bounds__(256) void k_gemm_qkv(
    const float* __restrict__ w, const float* __restrict__ x,
    const float* __restrict__ bias, f16* __restrict__ out,
    int* __restrict__ kmaxd_bits) {
  __shared__ f16 lds_b[64 * 256];  // 32KB [pix][ch-slot], swizzled
  int bm = blockIdx.x >> 6;   // 6
  int bn = blockIdx.x & 63;   // 64
  int tid = threadIdx.x;
  int wave = tid >> 6, lane = tid & 63;
  int r = lane & 15, g = lane >> 4;
  int m0 = bm * 128 + wave * 32;
  int n0 = bn * 64;
  kmaxd_bits[tid] = 0;  // all blocks store 0: benign, ready before dwconv
  // stage B: 1024 micro-tiles (16 pixel-groups x 64 channel-groups)
#pragma unroll
  for (int round = 0; round < 4; ++round) {
    int task = round * 256 + tid;
    int pg = task & 15, cg = task >> 4;  // pg: consecutive lanes -> coalesced
    int p0 = pg * 4, c0 = cg * 4;
    f32x4 v[4];
#pragma unroll
    for (int cc = 0; cc < 4; cc++)
      v[cc] = *(const f32x4*)&x[(c0 + cc) * HW + n0 + p0];
#pragma unroll
    for (int pp = 0; pp < 4; pp++) {
      int row = p0 + pp;
      f16x4 o;
#pragma unroll
      for (int cc = 0; cc < 4; cc++) o[cc] = (f16)v[cc][pp];  // RTN
      int byteoff =
          row * 512 + (((c0 >> 3) ^ (row & 7)) << 4) + (c0 & 4) * 2;
      *(f16x4*)((char*)lds_b + byteoff) = o;
    }
  }
  __syncthreads();
  f32x4 acc[2][4] = {};
  for (int kk = 0; kk < NC; kk += 32) {
    f16x8 a0 = load_a_f32(&w[(m0 + r) * NC + kk + g * 8]);
    f16x8 a1 = load_a_f32(&w[(m0 + 16 + r) * NC + kk + g * 8]);
    int sb = (kk >> 3) + g;  // data slot
#pragma unroll
    for (int nt = 0; nt < 4; nt++) {
      int row = nt * 16 + r;
      f16x8 bfr = *(const f16x8*)((char*)lds_b + row * 512 +
                                  ((sb ^ (row & 7)) * 16));
      acc[0][nt] = mfma16(a0, bfr, acc[0][nt]);
      acc[1][nt] = mfma16(a1, bfr, acc[1][nt]);
    }
  }
#pragma unroll
  for (int mg = 0; mg < 2; mg++) {
    int mbase = m0 + mg * 16 + g * 4;
    float bj[4];
#pragma unroll
    for (int j = 0; j < 4; j++) bj[j] = bias[mbase + j];
#pragma unroll
    for (int nt = 0; nt < 4; nt++)
#pragma unroll
      for (int j = 0; j < 4; j++)
        out[(mbase + j) * HW + n0 + nt * 16 + r] =
            (f16)(acc[mg][nt][j] + bj[j]);
  }
}

// ------------------- depthwise 11x11, pad 5, groups=768 --------------------
// 2 half-image blocks per channel; vectorized f16x8 image loads (R14).
// K-channel blocks compute per-(h,d) max|k| -> atomicMax (uniform branch).
__global__ __launch_bounds__(256) void k_dwconv(
    const f16* __restrict__ qkv, const float* __restrict__ wdw,
    const float* __restrict__ bdw, f16* __restrict__ q_nm,
    f16* __restrict__ k_nm, f16* __restrict__ v_cm,
    int* __restrict__ kmaxd_bits) {
  __shared__ float img[42 * 74];
  __shared__ float wgt[121];
  int b = blockIdx.x;
  int c = b >> 1, half = b & 1;
  int y0 = half * 32;
  int tid = threadIdx.x;
  for (int i = tid; i < 420; i += 256) {
    int row = i / 10, cc = i - row * 10;
    img[row * 74 + (cc < 5 ? cc : 64 + cc)] = 0.f;
  }
  const f16x8 zv = {};
  for (int task = tid; task < 336; task += 256) {
    int row = task >> 3, ch = task & 7;
    int y = y0 + row - 5;
    f16x8 v = ((unsigned)y < 64u)
                  ? *(const f16x8*)&qkv[c * HW + y * 64 + ch * 8]
                  : zv;
    float* dst = &img[row * 74 + 5 + ch * 8];
#pragma unroll
    for (int j = 0; j < 8; j++) dst[j] = (float)v[j];
  }
  for (int i = tid; i < 121; i += 256) wgt[i] = wdw[c * 121 + i];
  __syncthreads();
  float bias = bdw[c];
  int px0 = half * 2048 + tid * 8;
  int yl = tid >> 3;         // local row 0..31
  int x0 = (tid & 7) * 8;
  float acc[8] = {};
#pragma unroll
  for (int ky = 0; ky < 11; ky++) {
    const float* rp = &img[(yl + ky) * 74 + x0];
    float rv[18];
#pragma unroll
    for (int t = 0; t < 18; t++) rv[t] = rp[t];
#pragma unroll
    for (int kx = 0; kx < 11; kx++) {
      float wv = wgt[ky * 11 + kx];
#pragma unroll
      for (int p = 0; p < 8; p++) acc[p] = fmaf(rv[kx + p], wv, acc[p]);
    }
  }
  if (c < 256) {
    int h = c >> 5, d = c & 31;
#pragma unroll
    for (int p = 0; p < 8; p++)
      q_nm[(h * HW + px0 + p) * 32 + d] =
          (f16)((acc[p] + bias) * 0.28853900817779268f);  // 0.2*log2(e)
  } else if (c < 512) {
    int cc = c - 256;
    int h = cc >> 5, d = cc & 31;
    float m = 0.f;
#pragma unroll
    for (int p = 0; p < 8; p++) {
      float kv = acc[p] + bias;
      k_nm[(h * HW + px0 + p) * 32 + d] = (f16)kv;
      m = fmaxf(m, fabsf(kv));
    }
    // per-(h,d) max|k| reduce (uniform branch; reuse img LDS after sync)
    __syncthreads();
    img[tid] = m;
    __syncthreads();
    for (int off = 128; off > 0; off >>= 1) {
      if (tid < off) img[tid] = fmaxf(img[tid], img[tid + off]);
      __syncthreads();
    }
    if (tid == 0) atomicMax(&kmaxd_bits[cc], __float_as_int(img[0]));
  } else {
    int cc = c - 512;
#pragma unroll
    for (int p = 0; p < 8; p++)
      v_cm[cc * HW + px0 + p] = (f16)(acc[p] + bias);
  }
}

// ----------------------------- flash attention -----------------------------
// R14-verified structure. Block = 512 threads = 8 waves x 32 q-rows (256-row
// q-tile); key-quarter per block; 16 LDS-staged 64-key chunks, 4-deep,
// counted-vmcnt pipeline: issue gload for t+2 -> s_waitcnt vmcnt(2) -> raw
// s_barrier -> compute t. Waves 0-3 stage K, 4-7 stage V; K LDS [key][d]
// slot^=(key>>3)&3 both-sides; V LDS [d][key] slot^=(d&7). Fixed-shift
// softmax; setprio around MFMA clusters; pre-normalized f16 partials + f32 L.
// C_row = sum_d |q_d|*kmaxd[h][d] (per-coordinate bound, R18-verified).
__global__ __launch_bounds__(512, 4) void k_attn(
    const f16* __restrict__ q_nm, const f16* __restrict__ k_nm,
    const f16* __restrict__ v_cm, const int* __restrict__ kmaxd_bits,
    f16* __restrict__ o_part, float* __restrict__ l_part) {
  __shared__ f16 lds_k[4][2048];  // 4 x 4KB: [key 0..63][d-slot], swizzled
  __shared__ f16 lds_v[4][2048];  // 4 x 4KB: [d 0..31][key-slot], swizzled
  int bid = blockIdx.x;
  int h = bid & 7, kq = (bid >> 3) & 3, qt = bid >> 5;  // qt 0..15
  int tid = threadIdx.x;
  int wv = tid >> 6, lane = tid & 63;
  int r = lane & 15, g = lane >> 4;
  int n_base = qt * 256 + wv * 32;
  int m_lo = kq << 10;  // 1024 keys per block
  const f16* qh = q_nm + h * (HW * 32);
  const f16* kh = k_nm + h * (HW * 32) + m_lo * 32;
  const f16* vh = v_cm + h * (32 * HW) + m_lo;

  f16x8 bq0 = *(const f16x8*)&qh[(n_base + r) * 32 + g * 8];
  f16x8 bq1 = *(const f16x8*)&qh[(n_base + 16 + r) * 32 + g * 8];
  // ---- per-coordinate bound: C = sum_d |q_d| * kmaxd[h][d] ----
  const float* kmd = (const float*)kmaxd_bits + h * 32 + g * 8;
  f32x4 kd0 = *(const f32x4*)kmd;
  f32x4 kd1 = *(const f32x4*)(kmd + 4);
  float ba = 0.f, bb = 0.f;
#pragma unroll
  for (int j = 0; j < 4; j++) {
    ba = fmaf(fabsf((float)bq0[j]), kd0[j], ba);
    ba = fmaf(fabsf((float)bq0[4 + j]), kd1[j], ba);
    bb = fmaf(fabsf((float)bq1[j]), kd0[j], bb);
    bb = fmaf(fabsf((float)bq1[4 + j]), kd1[j], bb);
  }
  ba += __shfl_xor(ba, 16);
  ba += __shfl_xor(ba, 32);
  bb += __shfl_xor(bb, 16);
  bb += __shfl_xor(bb, 32);
  float mCa = 13.9f - ba;
  float mCb = 13.9f - bb;
  f32x4 cinitA = {mCa, mCa, mCa, mCa};
  f32x4 cinitB = {mCb, mCb, mCb, mCb};
  int pr = ((r & 12) << 1) | (r & 3);  // 8*(r>>2)+(r&3)
  f32x4 accA0 = {0.f, 0.f, 0.f, 0.f}, accA1 = {0.f, 0.f, 0.f, 0.f};
  f32x4 accB0 = {0.f, 0.f, 0.f, 0.f}, accB1 = {0.f, 0.f, 0.f, 0.f};
  float La = 0.f, Lb = 0.f;

  // ---- staging addresses (chunk 0); 16B per lane per chunk ----
  int l4 = lane >> 2, l3 = lane & 3;
  int kc = (wv & 3) * 16 + l4;
  int ku = (kc >> 3) & 3;
  const f16* kg_base = kh + kc * 32 + (l3 ^ ku) * 8;
  int t2v = (tid >= 256) ? tid - 256 : 0;
  int vd = t2v >> 3;
  int vkk = ((t2v & 7) ^ (vd & 7)) * 8;
  const f16* vg_base = vh + vd * HW + vkk;
  f16* kdst = &lds_k[0][0] + (wv & 3) * 512;   // + buf*2048
  f16* vdst = &lds_v[0][0] + (t2v >> 6) * 512; // wv-4

  // ---- consumer LDS byte offsets (loop-invariant) ----
  int u = r >> 2;
  int kslot = ((g ^ u) & 3) * 16;
  int ak0_off = pr * 64 + kslot;          // ks=0; ks=1: +2048
  int ak1_off = (pr + 4) * 64 + kslot;
  int vb_off0 = (r * 128 + g * 16) ^ ((r & 7) << 4);       // ks=0
  int vb_off1 = (r * 128 + 64 + g * 16) ^ ((r & 7) << 4);  // ks=1

  // ---- prologue: drain q/kmaxd loads, prefetch chunks 0,1 ----
  __builtin_amdgcn_s_waitcnt(0);
  if (wv < 4) {
    gload16(kg_base, kdst);
    gload16(kg_base + 2048, kdst + 2048);
  } else {
    gload16(vg_base, vdst);
    gload16(vg_base + 64, vdst + 2048);
  }

  for (int t = 0; t < 16; ++t) {
    int c2 = (t + 2 <= 15) ? t + 2 : 15;  // clamp: redundant restage, unread
    int b2 = (t + 2) & 3;
    if (wv < 4)
      gload16(kg_base + c2 * 2048, kdst + b2 * 2048);
    else
      gload16(vg_base + c2 * 64, vdst + b2 * 2048);
    asm volatile("s_waitcnt vmcnt(2)" ::: "memory");
    __builtin_amdgcn_sched_barrier(0);
    __builtin_amdgcn_s_barrier();
    __builtin_amdgcn_sched_barrier(0);
    const char* kb = (const char*)&lds_k[t & 3][0];
    const char* vb = (const char*)&lds_v[t & 3][0];
#pragma unroll
    for (int ks = 0; ks < 2; ++ks) {
      f16x8 ak0 = *(const f16x8*)(kb + ks * 2048 + ak0_off);
      f16x8 ak1 = *(const f16x8*)(kb + ks * 2048 + ak1_off);
      int vo = ks ? vb_off1 : vb_off0;
      f16x8 bv0 = *(const f16x8*)(vb + vo);          // V[d=r][...]
      f16x8 bv1 = *(const f16x8*)(vb + vo + 2048);   // V[d=16+r][...]
      __builtin_amdgcn_s_setprio(1);
      f32x4 sA0 = mfma16(ak0, bq0, cinitA);
      f32x4 sA1 = mfma16(ak1, bq0, cinitA);
      f32x4 sB0 = mfma16(ak0, bq1, cinitB);
      f32x4 sB1 = mfma16(ak1, bq1, cinitB);
      __builtin_amdgcn_s_setprio(0);
      float pA[8], pB[8];
#pragma unroll
      for (int j = 0; j < 4; j++) {
        pA[j] = EXP2(sA0[j]);
        pA[4 + j] = EXP2(sA1[j]);
        pB[j] = EXP2(sB0[j]);
        pB[4 + j] = EXP2(sB1[j]);
      }
      La += ((pA[0] + pA[1]) + (pA[2] + pA[3])) +
            ((pA[4] + pA[5]) + (pA[6] + pA[7]));
      Lb += ((pB[0] + pB[1]) + (pB[2] + pB[3])) +
            ((pB[4] + pB[5]) + (pB[6] + pB[7]));
      union { hf16x2 h2[4]; f16x8 v; } uA, uB;
#pragma unroll
      for (int j = 0; j < 4; j++) {
        uA.h2[j] = __builtin_amdgcn_cvt_pkrtz(pA[2 * j], pA[2 * j + 1]);
        uB.h2[j] = __builtin_amdgcn_cvt_pkrtz(pB[2 * j], pB[2 * j + 1]);
      }
      __builtin_amdgcn_s_setprio(1);
      accA0 = mfma16(uA.v, bv0, accA0);
      accA1 = mfma16(uA.v, bv1, accA1);
      accB0 = mfma16(uB.v, bv0, accB0);
      accB1 = mfma16(uB.v, bv1, accB1);
      __builtin_amdgcn_s_setprio(0);
    }
  }
  // ---- pre-normalized partials -> workspace (f16 O/L, f32 L) ----
  La += __shfl_xor(La, 16);
  La += __shfl_xor(La, 32);
  Lb += __shfl_xor(Lb, 16);
  Lb += __shfl_xor(Lb, 32);
  float ilA = 1.f / La, ilB = 1.f / Lb;
  f16* op = o_part + ((((size_t)kq * 8 + h) * HW) + n_base) * 32;
#pragma unroll
  for (int j = 0; j < 4; j++) {
    float ija = __shfl(ilA, 4 * g + j);  // 1/L for row n_base+4g+j
    float ijb = __shfl(ilB, 4 * g + j);  // 1/L for row n_base+16+4g+j
    op[(4 * g + j) * 32 + r] = (f16)(accA0[j] * ija);
    op[(4 * g + j) * 32 + 16 + r] = (f16)(accA1[j] * ija);
    op[(16 + 4 * g + j) * 32 + r] = (f16)(accB0[j] * ijb);
    op[(16 + 4 * g + j) * 32 + 16 + r] = (f16)(accB1[j] * ijb);
  }
  if (lane < 16) {
    l_part[(((size_t)kq * 8 + h) * HW) + n_base + r] = La;
    l_part[(((size_t)kq * 8 + h) * HW) + n_base + 16 + r] = Lb;
  }
}

// ---- GEMM2 (fused norm_o): out = relu(Wlin * combine(o_part) + b) + x -----
// B tile built during staging (combine the 4 key-quarter partials, same fmaf
// order/rounding as before); A rows (wlin) read f32-direct (RTN, bit-equal).
__global__ __launch_bounds__(256) void k_gemm_proj(
    const float* __restrict__ w, const f16* __restrict__ o_part,
    const float* __restrict__ l_part, const float* __restrict__ bias,
    const float* __restrict__ x, float* __restrict__ out) {
  __shared__ f16 lds_b[32 * 256];  // 16KB
  int bm = blockIdx.x >> 7;   // 4
  int bn = blockIdx.x & 127;  // 128 n-tiles of 32
  int tid = threadIdx.x;
  int wave = tid >> 6, lane = tid & 63;
  int r = lane & 15, g = lane >> 4;
  int m_row = bm * 64 + wave * 16 + r;
  int n0 = bn * 32;
  // fused combine-staging: 4 rounds x 256 threads = 1024 f16x8 tasks
#pragma unroll
  for (int round = 0; round < 4; ++round) {
    int task = round * 256 + tid;
    int row = task >> 5, grp = task & 31;      // grp = 8-ch group
    int h = grp >> 2, d0 = (grp & 3) * 8;
    size_t rbase = ((size_t)h * HW) + n0 + row;
    float Lq[4];
    f16x8 oq[4];
#pragma unroll
    for (int q = 0; q < 4; q++) {
      Lq[q] = l_part[(size_t)q * 8 * HW + rbase];
      oq[q] = *(const f16x8*)&o_part[((size_t)q * 8 * HW + rbase) * 32 + d0];
    }
    float inv = 1.f / ((Lq[0] + Lq[1]) + (Lq[2] + Lq[3]));
    f16x8 outv;
#pragma unroll
    for (int j = 0; j < 8; j++) {
      float o = 0.f;
#pragma unroll
      for (int q = 0; q < 4; q++) o = fmaf((float)oq[q][j], Lq[q], o);
      outv[j] = (f16)(o * inv);
    }
    *(f16x8*)((char*)lds_b + row * 512 + ((grp ^ (row & 7)) * 16)) = outv;
  }
  __syncthreads();
  f32x4 acc[2] = {};
  for (int kk = 0; kk < NC; kk += 32) {
    f16x8 a = load_a_f32(&w[m_row * NC + kk + g * 8]);
    int sb = (kk >> 3) + g;  // data slot
#pragma unroll
    for (int nt = 0; nt < 2; nt++) {
      int row = nt * 16 + r;
      f16x8 bfr = *(const f16x8*)((char*)lds_b + row * 512 +
                                  ((sb ^ (row & 7)) * 16));
      acc[nt] = mfma16(a, bfr, acc[nt]);
    }
  }
  int mbase = bm * 64 + wave * 16 + g * 4;
  float bj[4];
#pragma unroll
  for (int j = 0; j < 4; j++) bj[j] = bias[mbase + j];
#pragma unroll
  for (int nt = 0; nt < 2; nt++)
#pragma unroll
    for (int j = 0; j < 4; j++) {
      int m = mbase + j, n = n0 + nt * 16 + r;
      float v = fmaxf(acc[nt][j] + bj[j], 0.f) + x[m * HW + n];
      out[m * HW + n] = v;
    }
}

// ---------------------------------------------------------------------------
extern "C" void kernel_launch(void* const* d_in, const int* in_sizes, int n_in,
                              void* d_out, int out_size, void* d_ws,
                              size_t ws_size, hipStream_t stream) {
  const float* x = (const float*)d_in[0];
  const float* w_pw = (const float*)d_in[1];
  const float* b_pw = (const float*)d_in[2];
  const float* w_dw = (const float*)d_in[3];
  const float* b_dw = (const float*)d_in[4];
  const float* w_lin = (const float*)d_in[5];
  const float* b_lin = (const float*)d_in[6];
  float* out = (float*)d_out;

  char* ws = (char*)d_ws;
  f16* qkv = (f16*)(ws + 2621440);        // 768*4096*2     = 6291456
  f16* q_nm = (f16*)(ws + 15204352);      // 8*4096*32*2    = 2097152
  f16* k_nm = (f16*)(ws + 17301504);      // 2097152
  f16* v_cm = (f16*)(ws + 19398656);      // 2097152
  int* kmaxd_bits = (int*)(ws + 23724032);  // 256*4 = 1024 bytes
  // partials alias qkv region (qkv dead after k_dwconv):
  // o_part f16 4*8*4096*32*2 = 8388608; l_part f32 4*8*4096*4 = 524288
  f16* o_part = (f16*)(ws + 2621440);
  float* l_part = (float*)(ws + 2621440 + 8388608);  // ends 11534336 < 15204352

  k_gemm_qkv<<<384, 256, 0, stream>>>(w_pw, x, b_pw, qkv, kmaxd_bits);
  k_dwconv<<<1536, 256, 0, stream>>>(qkv, w_dw, b_dw, q_nm, k_nm, v_cm,
                                     kmaxd_bits);
  k_attn<<<512, 512, 0, stream>>>(q_nm, k_nm, v_cm, kmaxd_bits, o_part,
                                  l_part);
  k_gemm_proj<<<512, 256, 0, stream>>>(w_lin, o_part, l_part, b_lin, x, out);
}